// Round 12
// baseline (1828.373 us; speedup 1.0000x reference)
//
#include <hip/hip_runtime.h>
#include <math.h>

typedef _Float16 f16;
typedef _Float16 f16x8 __attribute__((ext_vector_type(8)));
typedef float f32x4 __attribute__((ext_vector_type(4)));

#define B_TOTAL 4096
#define T_STEPS 128
#define H 96
#define NB 8                // batch rows per block (half-filled 16-row m-tile)
#define NTH 384             // 6 waves — the proven no-spill shape
#define NBLK (B_TOTAL/NB)   // 512 blocks = 2 per CU -> 3 waves/SIMD
#define NROWS 16            // LDS tile rows incl. ghost rows 8..15

__device__ __forceinline__ float sigf(float v){ return 1.f/(1.f+__expf(-v)); }
__device__ __forceinline__ float tanhf_(float v){ float e=__expf(2.f*v); return 1.f-2.f/(e+1.f); }

// One LSTM layer per kernel, sequential over T, single barrier per step.
// Round 12 = round 11 math with NB=8 (512 blocks, 2/CU): occupancy experiment.
// Rows 8..15 of the LDS tile are ghost rows (computed, bounded, never stored).
template<int F, bool IS_L0, bool HAS_YSOUT, bool WRITE_HN, bool IS_LAST>
__global__ __launch_bounds__(NTH, 2)
void lstm_seq(const float* __restrict__ x,     // IS_L0 input
              f16* __restrict__ ys,            // relay [T][B][H] f16 (in/out)
              const float* __restrict__ Wi, const float* __restrict__ Wh,
              const float* __restrict__ bi, const float* __restrict__ bh,
              float* __restrict__ hn1g,        // WRITE_HN: store; IS_LAST: load
              const float* __restrict__ fc1_w, const float* __restrict__ fc1_b,
              const float* __restrict__ fc2_w, const float* __restrict__ fc2_b,
              const float* __restrict__ fc3_w, const float* __restrict__ fc3_b,
              float* __restrict__ out)
{
    constexpr int  KS   = (F + H + 31)/32;   // 4 (F=24) or 6 (F=96)
    constexpr int  KP   = KS*32;
    constexpr int  KPB  = KP*2;              // bytes per act row
    constexpr bool HAS_LO = IS_L0;           // lo plane only for x (slice 0)
    constexpr int  BUF  = NROWS*KP;

    __shared__ f16 sh[2*BUF];                    // hi plane, double-buffered
    __shared__ f16 sl[HAS_LO ? 2*BUF : 64];      // lo plane (L0 only)
    __shared__ float hsum[NB*96];                // head scratch (IS_LAST)
    __shared__ float z1[NB*16];
    __shared__ float z2[NB*8];

    const int tid=threadIdx.x, lane=tid&63, w=tid>>6;
    const int j15=lane&15, g4=lane>>4;
    const int u=16*w+j15;                        // unit 0..95
    const int row0=blockIdx.x*NB;

    for (int i=tid;i<2*BUF;i+=NTH) sh[i]=(f16)0.f;
    if constexpr (HAS_LO)
        for (int i=tid;i<2*BUF;i+=NTH) sl[i]=(f16)0.f;

    // weight B-frags, loaded once: lane holds W[j=96q+u][k=32s+8*g4+e]
    f16x8 Bf[4][KS];
#pragma unroll
    for (int q=0;q<4;++q){
        const int j=96*q+u;
#pragma unroll
        for (int s=0;s<KS;++s){
            f16x8 f;
#pragma unroll
            for (int e=0;e<8;++e){
                int k=32*s+8*g4+e;
                float v=0.f;
                if (k<F)        v=Wi[(size_t)j*F+k];
                else if (k-F<H) v=Wh[(size_t)j*H+(k-F)];
                f[e]=(f16)v;
            }
            Bf[q][s]=f;
        }
    }
    float bq[4];
#pragma unroll
    for (int q=0;q<4;++q) bq[q]=bi[96*q+u]+bh[96*q+u];

    float c4[4]={0.f,0.f,0.f,0.f};
    float h4[4]={0.f,0.f,0.f,0.f};
    float h4p[4]={0.f,0.f,0.f,0.f};              // h(t-1) for delayed ys store

    // staging maps (valid rows 0..7 -> 192 active threads)
    const int xr=tid/24, xk=tid-xr*24;           // IS_L0: 8 rows x 24 feats
    const bool xact = IS_L0 && (tid < NB*24);
    const float* xbase = xact ? x + (size_t)(row0+xr)*(T_STEPS*24) + xk : nullptr;
    const int xoff = xr*KPB + ((xk*2)^((xr&7)<<4));

    const int yi=tid*4, yr=yi/H, yk=yi-yr*H;     // else: 8 rows x 96 halves
    const bool yact = (!IS_L0) && (tid < (NB*H)/4);
    const f16* ybase = yact ? ys + (size_t)(row0+yr)*H + yk : nullptr;
    const int yoff = yr*KPB + ((yk*2)^((yr&7)<<4));

    // stage t=0 into buffer 0
    if constexpr (IS_L0){
        if (xact){
            float v=xbase[0];
            f16 vh=(f16)v, vl=(f16)(v-(float)vh);
            *(f16*)((char*)sh+xoff)=vh; *(f16*)((char*)sl+xoff)=vl;
        }
    } else {
        if (yact){
            uint2 v=*(const uint2*)(ybase);
            *(uint2*)((char*)sh+yoff)=v;
        }
    }
    __syncthreads();

    const int aswz=(j15&7)<<4;
    const int abase=j15*KPB;

#pragma unroll 1
    for (int t=0;t<T_STEPS;++t){
        const int cur=t&1, nxt=cur^1;
        const f16* ch=sh+cur*BUF;
        const f16* cl=HAS_LO ? sl+cur*BUF : nullptr;
        f16*       nh=sh+nxt*BUF;
        f16*       nl=HAS_LO ? sl+nxt*BUF : nullptr;

        // T14: issue next-step global input load now; consumed at step end
        float xv=0.f; uint2 yv={0u,0u};
        if (t+1<T_STEPS){
            if constexpr (IS_L0){ if (xact) xv = xbase[(size_t)(t+1)*24]; }
            else                { if (yact) yv = *(const uint2*)(ybase + (size_t)(t+1)*B_TOTAL*H); }
        }
        // delayed ys store: h(t-1) from registers; valid rows only (g4<2)
        if constexpr (HAS_YSOUT){
            if (t>0 && g4<2){
#pragma unroll
                for (int r=0;r<4;++r)
                    ys[((size_t)(t-1)*B_TOTAL+row0+4*g4+r)*H+u]=(f16)h4p[r];
            }
        }

        // ---- gate GEMM: two accumulator chains per gate (slice parity) ----
        f32x4 acch[4], accl[4];
#pragma unroll
        for (int q=0;q<4;++q){
            f32x4 a={bq[q],bq[q],bq[q],bq[q]}; acch[q]=a;
            f32x4 z={0.f,0.f,0.f,0.f};          accl[q]=z;
        }
#pragma unroll
        for (int s=0;s<KS;++s){
            int kb=((s*64+g4*16)^aswz);
            f16x8 ah=*(const f16x8*)((const char*)ch+abase+kb);
            if (s&1){
#pragma unroll
                for (int q=0;q<4;++q)
                    accl[q]=__builtin_amdgcn_mfma_f32_16x16x32_f16(ah,Bf[q][s],accl[q],0,0,0);
            } else {
#pragma unroll
                for (int q=0;q<4;++q)
                    acch[q]=__builtin_amdgcn_mfma_f32_16x16x32_f16(ah,Bf[q][s],acch[q],0,0,0);
            }
        }
        if constexpr (HAS_LO){  // x residual: slice 0 only
            int kb=((g4*16)^aswz);
            f16x8 al=*(const f16x8*)((const char*)cl+abase+kb);
#pragma unroll
            for (int q=0;q<4;++q)
                accl[q]=__builtin_amdgcn_mfma_f32_16x16x32_f16(al,Bf[q][0],accl[q],0,0,0);
        }
        // ---- cell update (registers; ghost rows bounded by sig/tanh) ----
#pragma unroll
        for (int r=0;r<4;++r){
            float iv=sigf(acch[0][r]+accl[0][r]);
            float fv=sigf(acch[1][r]+accl[1][r]);
            float gv=tanhf_(acch[2][r]+accl[2][r]);
            float ov=sigf(acch[3][r]+accl[3][r]);
            float c=fv*c4[r]+iv*gv;
            c4[r]=c;
            h4[r]=ov*tanhf_(c);
        }
        // ---- h (f16-only) -> buf[nxt]; hn/hsum at last step (valid rows) ----
#pragma unroll
        for (int r=0;r<4;++r){
            int row=4*g4+r, swz=(row&7)<<4;
            float h=h4[r];
            *(f16*)((char*)nh + row*KPB + (((F+u)*2)^swz)) = (f16)h;
            if constexpr (WRITE_HN){ if (t==T_STEPS-1 && row<NB) hn1g[(size_t)(row0+row)*H+u]=h; }
            if constexpr (IS_LAST) { if (t==T_STEPS-1 && row<NB) hsum[row*96+u]=h; }
            h4p[r]=h;
        }
        // ---- staged input -> buf[nxt] ----
        if (t+1<T_STEPS){
            if constexpr (IS_L0){
                if (xact){
                    f16 vh=(f16)xv, vl=(f16)(xv-(float)vh);
                    *(f16*)((char*)nh+xoff)=vh; *(f16*)((char*)nl+xoff)=vl;
                }
            } else {
                if (yact) *(uint2*)((char*)nh+yoff)=yv;
            }
        }
        __syncthreads();   // the only barrier per step
    }
    // final delayed ys store (t = T-1)
    if constexpr (HAS_YSOUT){
        if (g4<2){
#pragma unroll
            for (int r=0;r<4;++r)
                ys[((size_t)(T_STEPS-1)*B_TOTAL+row0+4*g4+r)*H+u]=(f16)h4p[r];
        }
    }

    if constexpr (IS_LAST){
        // hsum = h3(T-1) + hn1 (global, from layer-1 kernel), then fused head
        if (tid < (NB*96)/4){
            float4 v=*(const float4*)(hn1g + (size_t)row0*96 + tid*4);
            hsum[tid*4+0]+=v.x; hsum[tid*4+1]+=v.y;
            hsum[tid*4+2]+=v.z; hsum[tid*4+3]+=v.w;
        }
        __syncthreads();
        if (tid<NB*16){
            int r=tid>>4, jj=tid&15;
            float a=fc1_b[jj];
            for (int uu=0;uu<96;++uu) a+=fc1_w[jj*96+uu]*fmaxf(hsum[r*96+uu],0.f);
            z1[r*16+jj]=fmaxf(a,0.f);
        }
        __syncthreads();
        if (tid<NB*8){
            int r=tid>>3, jj=tid&7;
            float a=fc2_b[jj];
#pragma unroll
            for (int uu=0;uu<16;++uu) a+=fc2_w[jj*16+uu]*z1[r*16+uu];
            z2[r*8+jj]=fmaxf(a,0.f);
        }
        __syncthreads();
        if (tid<NB){
            float a=fc3_b[0];
#pragma unroll
            for (int uu=0;uu<8;++uu) a+=fc3_w[uu]*z2[tid*8+uu];
            out[row0+tid]=a;
        }
    }
}

extern "C" void kernel_launch(void* const* d_in, const int* in_sizes, int n_in,
                              void* d_out, int out_size, void* d_ws, size_t ws_size,
                              hipStream_t stream) {
    const float* x         = (const float*)d_in[0];
    const float* W_ih0     = (const float*)d_in[1];
    const float* W_ih_rest = (const float*)d_in[2];
    const float* W_hh      = (const float*)d_in[3];
    const float* b_ih      = (const float*)d_in[4];
    const float* b_hh      = (const float*)d_in[5];
    const float* fc1_w     = (const float*)d_in[6];
    const float* fc1_b     = (const float*)d_in[7];
    const float* fc2_w     = (const float*)d_in[8];
    const float* fc2_b     = (const float*)d_in[9];
    const float* fc3_w     = (const float*)d_in[10];
    const float* fc3_b     = (const float*)d_in[11];
    float* out = (float*)d_out;

    const size_t YS = (size_t)T_STEPS * B_TOTAL * H * sizeof(f16);   // ~100.7 MB
    const size_t HN = (size_t)B_TOTAL * H * sizeof(float);           // ~1.6 MB
    if (ws_size < YS + HN) {
        hipMemsetAsync(d_out, 0, (size_t)out_size * sizeof(float), stream);
        return;
    }
    f16*   ys   = (f16*)d_ws;
    float* hn1g = (float*)((char*)d_ws + YS);

    const int GH = 384 * 96;

    // layer 0: x -> ys
    lstm_seq<24, true,  true,  false, false><<<NBLK, NTH, 0, stream>>>(
        x, ys, W_ih0, W_hh, b_ih, b_hh, hn1g,
        fc1_w, fc1_b, fc2_w, fc2_b, fc3_w, fc3_b, out);
    // layer 1: ys -> ys (in-place), hn1 -> global
    lstm_seq<96, false, true,  true,  false><<<NBLK, NTH, 0, stream>>>(
        nullptr, ys, W_ih_rest,        W_hh + 1*GH, b_ih + 1*384, b_hh + 1*384, hn1g,
        fc1_w, fc1_b, fc2_w, fc2_b, fc3_w, fc3_b, out);
    // layer 2: ys -> ys
    lstm_seq<96, false, true,  false, false><<<NBLK, NTH, 0, stream>>>(
        nullptr, ys, W_ih_rest + 1*GH, W_hh + 2*GH, b_ih + 2*384, b_hh + 2*384, hn1g,
        fc1_w, fc1_b, fc2_w, fc2_b, fc3_w, fc3_b, out);
    // layer 3: ys -> (head fused) -> out
    lstm_seq<96, false, false, false, true ><<<NBLK, NTH, 0, stream>>>(
        nullptr, ys, W_ih_rest + 2*GH, W_hh + 3*GH, b_ih + 3*384, b_hh + 3*384, hn1g,
        fc1_w, fc1_b, fc2_w, fc2_b, fc3_w, fc3_b, out);
}

// Round 13
// 924.323 us; speedup vs baseline: 1.9781x; 1.9781x over previous
//
#include <hip/hip_runtime.h>
#include <math.h>

typedef _Float16 f16;
typedef _Float16 f16x8 __attribute__((ext_vector_type(8)));
typedef float f32x4 __attribute__((ext_vector_type(4)));

#define B_TOTAL 4096
#define T_STEPS 128
#define H 96
#define NB 16               // batch rows per block (one 16-row MFMA m-tile)
#define NTH 384             // 6 waves — the proven no-spill shape
#define NBLK (B_TOTAL/NB)   // 256 blocks = 1 per CU

__device__ __forceinline__ float sigf(float v){ return 1.f/(1.f+__expf(-v)); }
__device__ __forceinline__ float tanhf_(float v){ float e=__expf(2.f*v); return 1.f-2.f/(e+1.f); }

// LDS-only barrier: s_waitcnt lgkmcnt(0) + s_barrier, WITHOUT the vmcnt(0)
// drain __syncthreads() emits. The barrier orders only LDS traffic here:
// - global ys stores are consumed by the NEXT kernel (dispatch-end drain);
// - the t+1 prefetch load is consumed via a register dep (compiler emits a
//   counted vmcnt before that ds_write).
// sched_barrier(0) on both sides per rule #18 (no hoisting across asm waits).
__device__ __forceinline__ void lds_barrier(){
    __builtin_amdgcn_sched_barrier(0);
    asm volatile("s_waitcnt lgkmcnt(0)" ::: "memory");
    __builtin_amdgcn_s_barrier();
    __builtin_amdgcn_sched_barrier(0);
}

// One LSTM layer per kernel, sequential over T, single LDS-only barrier/step.
// = round 11 math (f16 recurrent h, parity-split acc chains, delayed ys
// store) with the vmcnt drain removed from the per-step barrier.
template<int F, bool IS_L0, bool HAS_YSOUT, bool WRITE_HN, bool IS_LAST>
__global__ __launch_bounds__(NTH, 2)   // cap 256 VGPR — proven no-spill budget
void lstm_seq(const float* __restrict__ x,     // IS_L0 input
              f16* __restrict__ ys,            // relay [T][B][H] f16 (in/out)
              const float* __restrict__ Wi, const float* __restrict__ Wh,
              const float* __restrict__ bi, const float* __restrict__ bh,
              float* __restrict__ hn1g,        // WRITE_HN: store; IS_LAST: load
              const float* __restrict__ fc1_w, const float* __restrict__ fc1_b,
              const float* __restrict__ fc2_w, const float* __restrict__ fc2_b,
              const float* __restrict__ fc3_w, const float* __restrict__ fc3_b,
              float* __restrict__ out)
{
    constexpr int  KS   = (F + H + 31)/32;   // 4 (F=24) or 6 (F=96)
    constexpr int  KP   = KS*32;
    constexpr int  KPB  = KP*2;              // bytes per act row
    constexpr bool HAS_LO = IS_L0;           // lo plane only for x (slice 0)
    constexpr int  BUF  = 16*KP;

    __shared__ f16 sh[2*BUF];                    // hi plane, double-buffered
    __shared__ f16 sl[HAS_LO ? 2*BUF : 64];      // lo plane (L0 only)
    __shared__ float hsum[16*96];                // head scratch (IS_LAST)
    __shared__ float z1[16*16];
    __shared__ float z2[16*8];

    const int tid=threadIdx.x, lane=tid&63, w=tid>>6;
    const int j15=lane&15, g4=lane>>4;
    const int u=16*w+j15;                        // unit 0..95
    const int row0=blockIdx.x*NB;

    for (int i=tid;i<2*BUF;i+=NTH) sh[i]=(f16)0.f;
    if constexpr (HAS_LO)
        for (int i=tid;i<2*BUF;i+=NTH) sl[i]=(f16)0.f;

    // weight B-frags, loaded once: lane holds W[j=96q+u][k=32s+8*g4+e]
    f16x8 Bf[4][KS];
#pragma unroll
    for (int q=0;q<4;++q){
        const int j=96*q+u;
#pragma unroll
        for (int s=0;s<KS;++s){
            f16x8 f;
#pragma unroll
            for (int e=0;e<8;++e){
                int k=32*s+8*g4+e;
                float v=0.f;
                if (k<F)        v=Wi[(size_t)j*F+k];
                else if (k-F<H) v=Wh[(size_t)j*H+(k-F)];
                f[e]=(f16)v;
            }
            Bf[q][s]=f;
        }
    }
    float bq[4];
#pragma unroll
    for (int q=0;q<4;++q) bq[q]=bi[96*q+u]+bh[96*q+u];

    float c4[4]={0.f,0.f,0.f,0.f};
    float h4[4]={0.f,0.f,0.f,0.f};
    float h4p[4]={0.f,0.f,0.f,0.f};              // h(t-1) for delayed ys store

    // staging maps
    const int xr=tid/24, xk=tid-xr*24;           // IS_L0: 16 rows x 24 feats
    const float* xbase = IS_L0 ? x + (size_t)(row0+xr)*(T_STEPS*24) + xk : nullptr;
    const int xoff = xr*KPB + ((xk*2)^((xr&7)<<4));

    const int yi=tid*4, yr=yi/H, yk=yi-yr*H;     // else: 16 rows x 96 halves
    const f16* ybase = (!IS_L0) ? ys + (size_t)(row0+yr)*H + yk : nullptr;
    const int yoff = yr*KPB + ((yk*2)^((yr&7)<<4));

    // stage t=0 into buffer 0
    if constexpr (IS_L0){
        float v=xbase[0];
        f16 vh=(f16)v, vl=(f16)(v-(float)vh);
        *(f16*)((char*)sh+xoff)=vh; *(f16*)((char*)sl+xoff)=vl;
    } else {
        uint2 v=*(const uint2*)(ybase);
        *(uint2*)((char*)sh+yoff)=v;
    }
    __syncthreads();

    const int aswz=(j15&7)<<4;
    const int abase=j15*KPB;

#pragma unroll 1
    for (int t=0;t<T_STEPS;++t){
        const int cur=t&1, nxt=cur^1;
        const f16* ch=sh+cur*BUF;
        const f16* cl=HAS_LO ? sl+cur*BUF : nullptr;
        f16*       nh=sh+nxt*BUF;
        f16*       nl=HAS_LO ? sl+nxt*BUF : nullptr;

        // T14: issue next-step global input load FIRST (before any stores),
        // then pin with sched_barrier so it can't sink to its use.
        float xv=0.f; uint2 yv={0u,0u};
        if (t+1<T_STEPS){
            if constexpr (IS_L0) xv = xbase[(size_t)(t+1)*24];
            else                 yv = *(const uint2*)(ybase + (size_t)(t+1)*B_TOTAL*H);
        }
        __builtin_amdgcn_sched_barrier(0);

        // delayed ys store: h(t-1) from registers (drains off the chain)
        if constexpr (HAS_YSOUT){
            if (t>0){
#pragma unroll
                for (int r=0;r<4;++r)
                    ys[((size_t)(t-1)*B_TOTAL+row0+4*g4+r)*H+u]=(f16)h4p[r];
            }
        }

        // ---- gate GEMM: two accumulator chains per gate (slice parity) ----
        f32x4 acch[4], accl[4];
#pragma unroll
        for (int q=0;q<4;++q){
            f32x4 a={bq[q],bq[q],bq[q],bq[q]}; acch[q]=a;
            f32x4 z={0.f,0.f,0.f,0.f};          accl[q]=z;
        }
#pragma unroll
        for (int s=0;s<KS;++s){
            int kb=((s*64+g4*16)^aswz);
            f16x8 ah=*(const f16x8*)((const char*)ch+abase+kb);
            if (s&1){
#pragma unroll
                for (int q=0;q<4;++q)
                    accl[q]=__builtin_amdgcn_mfma_f32_16x16x32_f16(ah,Bf[q][s],accl[q],0,0,0);
            } else {
#pragma unroll
                for (int q=0;q<4;++q)
                    acch[q]=__builtin_amdgcn_mfma_f32_16x16x32_f16(ah,Bf[q][s],acch[q],0,0,0);
            }
        }
        if constexpr (HAS_LO){  // x residual: slice 0 only
            int kb=((g4*16)^aswz);
            f16x8 al=*(const f16x8*)((const char*)cl+abase+kb);
#pragma unroll
            for (int q=0;q<4;++q)
                accl[q]=__builtin_amdgcn_mfma_f32_16x16x32_f16(al,Bf[q][0],accl[q],0,0,0);
        }
        // ---- cell update (registers) ----
#pragma unroll
        for (int r=0;r<4;++r){
            float iv=sigf(acch[0][r]+accl[0][r]);
            float fv=sigf(acch[1][r]+accl[1][r]);
            float gv=tanhf_(acch[2][r]+accl[2][r]);
            float ov=sigf(acch[3][r]+accl[3][r]);
            float c=fv*c4[r]+iv*gv;
            c4[r]=c;
            h4[r]=ov*tanhf_(c);
        }
        // ---- h (f16-only) -> buf[nxt]; hn/hsum at last step ----
#pragma unroll
        for (int r=0;r<4;++r){
            int row=4*g4+r, swz=(row&7)<<4;
            float h=h4[r];
            *(f16*)((char*)nh + row*KPB + (((F+u)*2)^swz)) = (f16)h;
            if constexpr (WRITE_HN){ if (t==T_STEPS-1) hn1g[(size_t)(row0+row)*H+u]=h; }
            if constexpr (IS_LAST) { if (t==T_STEPS-1) hsum[row*96+u]=h; }
            h4p[r]=h;
        }
        // ---- staged input -> buf[nxt] (counted vmcnt on the load only) ----
        if (t+1<T_STEPS){
            if constexpr (IS_L0){
                f16 vh=(f16)xv, vl=(f16)(xv-(float)vh);
                *(f16*)((char*)nh+xoff)=vh; *(f16*)((char*)nl+xoff)=vl;
            } else {
                *(uint2*)((char*)nh+yoff)=yv;
            }
        }
        lds_barrier();   // LDS-only barrier: no vmcnt(0) drain on the chain
    }
    // final delayed ys store (t = T-1)
    if constexpr (HAS_YSOUT){
#pragma unroll
        for (int r=0;r<4;++r)
            ys[((size_t)(T_STEPS-1)*B_TOTAL+row0+4*g4+r)*H+u]=(f16)h4p[r];
    }

    if constexpr (IS_LAST){
        // hsum = h3(T-1) + hn1 (global, from layer-1 kernel), then fused head
        {
            float4 v=*(const float4*)(hn1g + (size_t)row0*96 + tid*4);
            hsum[tid*4+0]+=v.x; hsum[tid*4+1]+=v.y;
            hsum[tid*4+2]+=v.z; hsum[tid*4+3]+=v.w;
        }
        __syncthreads();
        if (tid<256){
            int r=tid>>4, jj=tid&15;
            float a=fc1_b[jj];
            for (int uu=0;uu<96;++uu) a+=fc1_w[jj*96+uu]*fmaxf(hsum[r*96+uu],0.f);
            z1[r*16+jj]=fmaxf(a,0.f);
        }
        __syncthreads();
        if (tid<128){
            int r=tid>>3, jj=tid&7;
            float a=fc2_b[jj];
#pragma unroll
            for (int uu=0;uu<16;++uu) a+=fc2_w[jj*16+uu]*z1[r*16+uu];
            z2[r*8+jj]=fmaxf(a,0.f);
        }
        __syncthreads();
        if (tid<16){
            float a=fc3_b[0];
#pragma unroll
            for (int uu=0;uu<8;++uu) a+=fc3_w[uu]*z2[tid*8+uu];
            out[row0+tid]=a;
        }
    }
}

extern "C" void kernel_launch(void* const* d_in, const int* in_sizes, int n_in,
                              void* d_out, int out_size, void* d_ws, size_t ws_size,
                              hipStream_t stream) {
    const float* x         = (const float*)d_in[0];
    const float* W_ih0     = (const float*)d_in[1];
    const float* W_ih_rest = (const float*)d_in[2];
    const float* W_hh      = (const float*)d_in[3];
    const float* b_ih      = (const float*)d_in[4];
    const float* b_hh      = (const float*)d_in[5];
    const float* fc1_w     = (const float*)d_in[6];
    const float* fc1_b     = (const float*)d_in[7];
    const float* fc2_w     = (const float*)d_in[8];
    const float* fc2_b     = (const float*)d_in[9];
    const float* fc3_w     = (const float*)d_in[10];
    const float* fc3_b     = (const float*)d_in[11];
    float* out = (float*)d_out;

    const size_t YS = (size_t)T_STEPS * B_TOTAL * H * sizeof(f16);   // ~100.7 MB
    const size_t HN = (size_t)B_TOTAL * H * sizeof(float);           // ~1.6 MB
    if (ws_size < YS + HN) {
        hipMemsetAsync(d_out, 0, (size_t)out_size * sizeof(float), stream);
        return;
    }
    f16*   ys   = (f16*)d_ws;
    float* hn1g = (float*)((char*)d_ws + YS);

    const int GH = 384 * 96;

    // layer 0: x -> ys
    lstm_seq<24, true,  true,  false, false><<<NBLK, NTH, 0, stream>>>(
        x, ys, W_ih0, W_hh, b_ih, b_hh, hn1g,
        fc1_w, fc1_b, fc2_w, fc2_b, fc3_w, fc3_b, out);
    // layer 1: ys -> ys (in-place), hn1 -> global
    lstm_seq<96, false, true,  true,  false><<<NBLK, NTH, 0, stream>>>(
        nullptr, ys, W_ih_rest,        W_hh + 1*GH, b_ih + 1*384, b_hh + 1*384, hn1g,
        fc1_w, fc1_b, fc2_w, fc2_b, fc3_w, fc3_b, out);
    // layer 2: ys -> ys
    lstm_seq<96, false, true,  false, false><<<NBLK, NTH, 0, stream>>>(
        nullptr, ys, W_ih_rest + 1*GH, W_hh + 2*GH, b_ih + 2*384, b_hh + 2*384, hn1g,
        fc1_w, fc1_b, fc2_w, fc2_b, fc3_w, fc3_b, out);
    // layer 3: ys -> (head fused) -> out
    lstm_seq<96, false, false, false, true ><<<NBLK, NTH, 0, stream>>>(
        nullptr, ys, W_ih_rest + 2*GH, W_hh + 3*GH, b_ih + 3*384, b_hh + 3*384, hn1g,
        fc1_w, fc1_b, fc2_w, fc2_b, fc3_w, fc3_b, out);
}

// Round 14
// 830.810 us; speedup vs baseline: 2.2007x; 1.1126x over previous
//
#include <hip/hip_runtime.h>
#include <math.h>

typedef _Float16 f16;
typedef _Float16 f16x8 __attribute__((ext_vector_type(8)));
typedef float f32x4 __attribute__((ext_vector_type(4)));

#define B_TOTAL 4096
#define T_STEPS 128
#define H 96
#define NB 16               // batch rows per block (one 16-row MFMA m-tile)
#define NTH 768             // 12 waves = 3 waves/SIMD (the latency-hiding fix)
#define NBLK (B_TOTAL/NB)   // 256 blocks = 1 per CU
#define GST 100             // gbuf row stride in f32 (pad -> 2-way conflicts = free)

__device__ __forceinline__ float sigf(float v){ return 1.f/(1.f+__expf(-v)); }
__device__ __forceinline__ float tanhf_(float v){ float e=__expf(2.f*v); return 1.f-2.f/(e+1.f); }

// LDS-only barrier (R13): no vmcnt(0) drain; orders LDS traffic only.
__device__ __forceinline__ void lds_barrier(){
    __builtin_amdgcn_sched_barrier(0);
    asm volatile("s_waitcnt lgkmcnt(0)" ::: "memory");
    __builtin_amdgcn_s_barrier();
    __builtin_amdgcn_sched_barrier(0);
}

// One LSTM layer per kernel, sequential over T. 12-wave split:
//  MFMA phase: wave w owns unit-group g=w>>1, gates q0=2*(w&1), q0+1
//              (Bf[2][KS] = 48 VGPR/wave). Gates go to gbuf (f32, exact).
//  Elementwise phase: all 768 threads, 2 cells each (thread t -> unit t>>3,
//              rows (t&7)*2, +1): nonlin + c update + h->LDS(+ys).
// Two lds_barriers per step. h recurrent state is f16 (proven, absmax 6.1e-5).
template<int F, bool IS_L0, bool HAS_YSOUT, bool WRITE_HN, bool IS_LAST>
__global__ __launch_bounds__(NTH, 1)
void lstm_seq(const float* __restrict__ x,     // IS_L0 input
              f16* __restrict__ ys,            // relay [T][B][H] f16 (in/out)
              const float* __restrict__ Wi, const float* __restrict__ Wh,
              const float* __restrict__ bi, const float* __restrict__ bh,
              float* __restrict__ hn1g,        // WRITE_HN: store; IS_LAST: load
              const float* __restrict__ fc1_w, const float* __restrict__ fc1_b,
              const float* __restrict__ fc2_w, const float* __restrict__ fc2_b,
              const float* __restrict__ fc3_w, const float* __restrict__ fc3_b,
              float* __restrict__ out)
{
    constexpr int  KS   = (F + H + 31)/32;   // 4 (F=24) or 6 (F=96)
    constexpr int  KP   = KS*32;
    constexpr int  KPB  = KP*2;              // bytes per act row
    constexpr bool HAS_LO = IS_L0;           // lo plane only for x (slice 0)
    constexpr int  BUF  = 16*KP;

    __shared__ f16 sh[2*BUF];                    // hi act plane, double-buffered
    __shared__ f16 sl[HAS_LO ? 2*BUF : 64];      // lo plane (L0 only)
    __shared__ float gbuf[4*16*GST];             // [gate][row][unit] f32
    __shared__ float hsum[IS_LAST ? 16*96 : 16]; // head scratch
    __shared__ float z1[IS_LAST ? 16*16 : 16];
    __shared__ float z2[IS_LAST ? 16*8  : 16];

    const int tid=threadIdx.x, lane=tid&63, w=tid>>6;   // w: 0..11
    const int j15=lane&15, g4=lane>>4;
    const int g  = w>>1;                     // unit group 0..5
    const int q0 = (w&1)*2;                  // gates q0, q0+1
    const int u  = 16*g + j15;               // unit 0..95 (MFMA role)
    const int row0=blockIdx.x*NB;

    // elementwise role: 2 cells per thread, unit-major
    const int eu  = tid>>3;                  // unit 0..95
    const int er0 = (tid&7)*2;               // rows er0, er0+1

    for (int i=tid;i<2*BUF;i+=NTH) sh[i]=(f16)0.f;
    if constexpr (HAS_LO)
        for (int i=tid;i<2*BUF;i+=NTH) sl[i]=(f16)0.f;

    // weight B-frags: lane holds W[j=96*(q0+qq)+u][k=32s+8*g4+e]
    f16x8 Bf[2][KS];
#pragma unroll
    for (int qq=0;qq<2;++qq){
        const int j=96*(q0+qq)+u;
#pragma unroll
        for (int s=0;s<KS;++s){
            f16x8 f;
#pragma unroll
            for (int e=0;e<8;++e){
                int k=32*s+8*g4+e;
                float v=0.f;
                if (k<F)        v=Wi[(size_t)j*F+k];
                else if (k-F<H) v=Wh[(size_t)j*H+(k-F)];
                f[e]=(f16)v;
            }
            Bf[qq][s]=f;
        }
    }
    float bq[2];
#pragma unroll
    for (int qq=0;qq<2;++qq) bq[qq]=bi[96*(q0+qq)+u]+bh[96*(q0+qq)+u];

    float c2[2]={0.f,0.f};
    float h2p[2]={0.f,0.f};                  // h(t-1) for delayed ys store

    // delayed-ys incremental pointers (avoid per-step 64-bit mul)
    f16* yspA=nullptr; f16* yspB=nullptr;
    if constexpr (HAS_YSOUT){
        yspA = ys + (size_t)(row0+er0  )*H + eu;
        yspB = ys + (size_t)(row0+er0+1)*H + eu;
    }

    // staging maps
    const int xr=tid/24, xk=tid-xr*24;           // IS_L0: 384 active threads
    const bool xact = IS_L0 && (tid < NB*24);
    const float* xbase = xact ? x + (size_t)(row0+xr)*(T_STEPS*24) + xk : nullptr;
    const int xoff = xr*KPB + ((xk*2)^((xr&7)<<4));

    const int yi=tid*2, yr=yi/H, yk=yi-yr*H;     // else: all 768 threads, u32 each
    const f16* ybase = (!IS_L0) ? ys + (size_t)(row0+yr)*H + yk : nullptr;
    const int yoff = yr*KPB + ((yk*2)^((yr&7)<<4));

    // stage t=0 into buffer 0
    if constexpr (IS_L0){
        if (xact){
            float v=xbase[0];
            f16 vh=(f16)v, vl=(f16)(v-(float)vh);
            *(f16*)((char*)sh+xoff)=vh; *(f16*)((char*)sl+xoff)=vl;
        }
    } else {
        unsigned v=*(const unsigned*)(ybase);
        *(unsigned*)((char*)sh+yoff)=v;
    }
    __syncthreads();

    const int aswz=(j15&7)<<4;
    const int abase=j15*KPB;

#pragma unroll 1
    for (int t=0;t<T_STEPS;++t){
        const int cur=t&1, nxt=cur^1;
        const f16* ch=sh+cur*BUF;
        const f16* cl=HAS_LO ? sl+cur*BUF : nullptr;
        f16*       nh=sh+nxt*BUF;
        f16*       nl=HAS_LO ? sl+nxt*BUF : nullptr;

        // T14: issue next-step global input load first; pin against sinking
        float xv=0.f; unsigned yv=0u;
        if (t+1<T_STEPS){
            if constexpr (IS_L0){ if (xact) xv = xbase[(size_t)(t+1)*24]; }
            else                  yv = *(const unsigned*)(ybase + (size_t)(t+1)*B_TOTAL*H);
        }
        __builtin_amdgcn_sched_barrier(0);

        // delayed ys store of h(t-1): incremental pointers, off the chain
        if constexpr (HAS_YSOUT){
            if (t>0){
                *yspA=(f16)h2p[0]; *yspB=(f16)h2p[1];
                yspA += (size_t)B_TOTAL*H; yspB += (size_t)B_TOTAL*H;
            }
        }

        // ---- MFMA phase: 2 gates x (parity-split chains, depth<=3) ----
        f32x4 acc[2][2];
#pragma unroll
        for (int qq=0;qq<2;++qq){
            f32x4 a={bq[qq],bq[qq],bq[qq],bq[qq]}; acc[qq][0]=a;
            f32x4 z={0.f,0.f,0.f,0.f};              acc[qq][1]=z;
        }
#pragma unroll
        for (int s=0;s<KS;++s){
            int kb=((s*64+g4*16)^aswz);
            f16x8 ah=*(const f16x8*)((const char*)ch+abase+kb);
            if (s&1){
                acc[0][1]=__builtin_amdgcn_mfma_f32_16x16x32_f16(ah,Bf[0][s],acc[0][1],0,0,0);
                acc[1][1]=__builtin_amdgcn_mfma_f32_16x16x32_f16(ah,Bf[1][s],acc[1][1],0,0,0);
            } else {
                acc[0][0]=__builtin_amdgcn_mfma_f32_16x16x32_f16(ah,Bf[0][s],acc[0][0],0,0,0);
                acc[1][0]=__builtin_amdgcn_mfma_f32_16x16x32_f16(ah,Bf[1][s],acc[1][0],0,0,0);
            }
        }
        if constexpr (HAS_LO){  // x residual: slice 0 -> parity-1 chains
            int kb=((g4*16)^aswz);
            f16x8 al=*(const f16x8*)((const char*)cl+abase+kb);
            acc[0][1]=__builtin_amdgcn_mfma_f32_16x16x32_f16(al,Bf[0][0],acc[0][1],0,0,0);
            acc[1][1]=__builtin_amdgcn_mfma_f32_16x16x32_f16(al,Bf[1][0],acc[1][1],0,0,0);
        }
        // gates -> gbuf (f32, exact): C[row=4*g4+r][col=u]
#pragma unroll
        for (int qq=0;qq<2;++qq)
#pragma unroll
        for (int r=0;r<4;++r)
            gbuf[(q0+qq)*16*GST + (4*g4+r)*GST + u] = acc[qq][0][r]+acc[qq][1][r];
        lds_barrier();   // gates visible to elementwise waves

        // ---- elementwise phase: 2 cells per thread ----
#pragma unroll
        for (int s2=0;s2<2;++s2){
            int row=er0+s2;
            float gi=gbuf[0*16*GST + row*GST + eu];
            float gf=gbuf[1*16*GST + row*GST + eu];
            float gg=gbuf[2*16*GST + row*GST + eu];
            float go=gbuf[3*16*GST + row*GST + eu];
            float iv=sigf(gi), fv=sigf(gf), gv=tanhf_(gg), ov=sigf(go);
            float c=fv*c2[s2]+iv*gv;
            c2[s2]=c;
            float h=ov*tanhf_(c);
            *(f16*)((char*)nh + row*KPB + (((F+eu)*2)^((row&7)<<4))) = (f16)h;
            if constexpr (WRITE_HN){ if (t==T_STEPS-1) hn1g[(size_t)(row0+row)*H+eu]=h; }
            if constexpr (IS_LAST) { if (t==T_STEPS-1) hsum[row*96+eu]=h; }
            h2p[s2]=h;
        }
        // ---- staged input -> buf[nxt] ----
        if (t+1<T_STEPS){
            if constexpr (IS_L0){
                if (xact){
                    f16 vh=(f16)xv, vl=(f16)(xv-(float)vh);
                    *(f16*)((char*)nh+xoff)=vh; *(f16*)((char*)nl+xoff)=vl;
                }
            } else {
                *(unsigned*)((char*)nh+yoff)=yv;
            }
        }
        lds_barrier();   // h + staged input visible for next step's MFMA
    }
    // final delayed ys store (t = T-1)
    if constexpr (HAS_YSOUT){
        *yspA=(f16)h2p[0]; *yspB=(f16)h2p[1];
    }

    if constexpr (IS_LAST){
        // hsum = h3(T-1) + hn1 (global, from layer-1 kernel), then fused head
        {
            float2 v=*(const float2*)(hn1g + (size_t)row0*96 + tid*2);
            hsum[tid*2+0]+=v.x; hsum[tid*2+1]+=v.y;
        }
        __syncthreads();
        if (tid<256){
            int r=tid>>4, jj=tid&15;
            float a=fc1_b[jj];
            for (int uu=0;uu<96;++uu) a+=fc1_w[jj*96+uu]*fmaxf(hsum[r*96+uu],0.f);
            z1[r*16+jj]=fmaxf(a,0.f);
        }
        __syncthreads();
        if (tid<128){
            int r=tid>>3, jj=tid&7;
            float a=fc2_b[jj];
#pragma unroll
            for (int uu=0;uu<16;++uu) a+=fc2_w[jj*16+uu]*z1[r*16+uu];
            z2[r*8+jj]=fmaxf(a,0.f);
        }
        __syncthreads();
        if (tid<16){
            float a=fc3_b[0];
#pragma unroll
            for (int uu=0;uu<8;++uu) a+=fc3_w[uu]*z2[tid*8+uu];
            out[row0+tid]=a;
        }
    }
}

extern "C" void kernel_launch(void* const* d_in, const int* in_sizes, int n_in,
                              void* d_out, int out_size, void* d_ws, size_t ws_size,
                              hipStream_t stream) {
    const float* x         = (const float*)d_in[0];
    const float* W_ih0     = (const float*)d_in[1];
    const float* W_ih_rest = (const float*)d_in[2];
    const float* W_hh      = (const float*)d_in[3];
    const float* b_ih      = (const float*)d_in[4];
    const float* b_hh      = (const float*)d_in[5];
    const float* fc1_w     = (const float*)d_in[6];
    const float* fc1_b     = (const float*)d_in[7];
    const float* fc2_w     = (const float*)d_in[8];
    const float* fc2_b     = (const float*)d_in[9];
    const float* fc3_w     = (const float*)d_in[10];
    const float* fc3_b     = (const float*)d_in[11];
    float* out = (float*)d_out;

    const size_t YS = (size_t)T_STEPS * B_TOTAL * H * sizeof(f16);   // ~100.7 MB
    const size_t HN = (size_t)B_TOTAL * H * sizeof(float);           // ~1.6 MB
    if (ws_size < YS + HN) {
        hipMemsetAsync(d_out, 0, (size_t)out_size * sizeof(float), stream);
        return;
    }
    f16*   ys   = (f16*)d_ws;
    float* hn1g = (float*)((char*)d_ws + YS);

    const int GH = 384 * 96;

    // layer 0: x -> ys
    lstm_seq<24, true,  true,  false, false><<<NBLK, NTH, 0, stream>>>(
        x, ys, W_ih0, W_hh, b_ih, b_hh, hn1g,
        fc1_w, fc1_b, fc2_w, fc2_b, fc3_w, fc3_b, out);
    // layer 1: ys -> ys (in-place), hn1 -> global
    lstm_seq<96, false, true,  true,  false><<<NBLK, NTH, 0, stream>>>(
        nullptr, ys, W_ih_rest,        W_hh + 1*GH, b_ih + 1*384, b_hh + 1*384, hn1g,
        fc1_w, fc1_b, fc2_w, fc2_b, fc3_w, fc3_b, out);
    // layer 2: ys -> ys
    lstm_seq<96, false, true,  false, false><<<NBLK, NTH, 0, stream>>>(
        nullptr, ys, W_ih_rest + 1*GH, W_hh + 2*GH, b_ih + 2*384, b_hh + 2*384, hn1g,
        fc1_w, fc1_b, fc2_w, fc2_b, fc3_w, fc3_b, out);
    // layer 3: ys -> (head fused) -> out
    lstm_seq<96, false, false, false, true ><<<NBLK, NTH, 0, stream>>>(
        nullptr, ys, W_ih_rest + 2*GH, W_hh + 3*GH, b_ih + 3*384, b_hh + 3*384, hn1g,
        fc1_w, fc1_b, fc2_w, fc2_b, fc3_w, fc3_b, out);
}